// Round 6
// baseline (110.175 us; speedup 1.0000x reference)
//
#include <hip/hip_runtime.h>

#define NL 12
#define NB 2
#define NS 2048
#define ND 1024
#define NDK 256
#define NBS (NB*NS)   // 4096

typedef __attribute__((ext_vector_type(8))) short short8;
typedef __attribute__((ext_vector_type(4))) short short4v;
typedef __attribute__((ext_vector_type(4))) float floatx4;

__device__ __forceinline__ unsigned short f2bf(float f) {
    unsigned int u = __float_as_uint(f);
    u += 0x7FFFu + ((u >> 16) & 1u);
    return (unsigned short)(u >> 16);
}
__device__ __forceinline__ short f2bfs(float f) { return (short)f2bf(f); }
__device__ __forceinline__ float bf2f(short s) {
    return __uint_as_float(((unsigned int)(unsigned short)s) << 16);
}

// K1: blocks [0,256): W2t[d][d'] = (sum_k Wk[k][d]*Wq[k][d']) * lnw[d']  (bf16, MFMA)
//     blocks [256,264): c1v = Wk^T(Wq*lnw), c2v = Wk^T(Wq*lnb)  (fp32 matvecs)
__global__ void k_prep(const float* __restrict__ Wq, const float* __restrict__ Wk,
                       const float* __restrict__ lnw, const float* __restrict__ lnb,
                       unsigned short* __restrict__ W2t,
                       float* __restrict__ c1v, float* __restrict__ c2v) {
    const int tid = threadIdx.x;
    if (blockIdx.x < 256) {
        const int lane = tid & 63, wv = tid >> 6;
        const int wid = blockIdx.x * 4 + wv;      // 0..1023
        const int tm = wid >> 4;                  // d-tile (rows of W2t)
        const int tnb = wid & 15;                 // d'-tile (64 cols)
        const int lr = lane & 15, kh = lane >> 4;
        floatx4 acc[4];
#pragma unroll
        for (int c = 0; c < 4; ++c) acc[c] = (floatx4){0.f, 0.f, 0.f, 0.f};
#pragma unroll 2
        for (int kb = 0; kb < 8; ++kb) {
            const float* Ab = Wk + (size_t)(kb * 32 + kh * 8) * ND + tm * 16 + lr;
            const float* Bb = Wq + (size_t)(kb * 32 + kh * 8) * ND + tnb * 64 + lr;
            short8 a;
#pragma unroll
            for (int j = 0; j < 8; ++j) a[j] = f2bfs(Ab[(size_t)j * ND]);
#pragma unroll
            for (int c = 0; c < 4; ++c) {
                short8 b;
#pragma unroll
                for (int j = 0; j < 8; ++j) b[j] = f2bfs(Bb[(size_t)j * ND + c * 16]);
                acc[c] = __builtin_amdgcn_mfma_f32_16x16x32_bf16(a, b, acc[c], 0, 0, 0);
            }
        }
#pragma unroll
        for (int c = 0; c < 4; ++c) {
            const int col = tnb * 64 + c * 16 + lr;
            const float wc_ = lnw[col];
#pragma unroll
            for (int r = 0; r < 4; ++r)
                W2t[(size_t)(tm * 16 + kh * 4 + r) * ND + col] = f2bf(acc[c][r] * wc_);
        }
        return;
    }
    // matvec blocks
    __shared__ float z1[NDK], z2[NDK];
    const int bid2 = blockIdx.x - 256;            // 0..7 -> 128 outputs each
    {   // phase 1: z[k] = sum_d' Wq[k][d'] * {w,b}[d'], k = tid (0..255)
        const float4* wq = (const float4*)(Wq + (size_t)tid * ND);
        const float4* w4 = (const float4*)lnw;
        const float4* b4 = (const float4*)lnb;
        float a1 = 0.f, a2 = 0.f;
#pragma unroll 4
        for (int i = 0; i < ND / 4; ++i) {
            float4 q = wq[i], ww = w4[i], bb = b4[i];
            a1 += q.x*ww.x + q.y*ww.y + q.z*ww.z + q.w*ww.w;
            a2 += q.x*bb.x + q.y*bb.y + q.z*bb.z + q.w*bb.w;
        }
        z1[tid] = a1; z2[tid] = a2;
    }
    __syncthreads();
    if (tid < 128) {
        const int d = bid2 * 128 + tid;
        float s1 = 0.f, s2 = 0.f;
#pragma unroll 4
        for (int k = 0; k < NDK; ++k) {
            float wk = Wk[(size_t)k * ND + d];
            s1 += wk * z1[k]; s2 += wk * z2[k];
        }
        c1v[d] = s1; c2v[d] = s2;
    }
}

// K2: V (4096x1024 bf16) = LN-folded GEMM on raw x11.
//   y = (bf16(x11)) @ W2t^T ;  V = rstd*y + c2v - rstd*mu*c1v  (per-row stats in-block)
#define BM 64
#define BN 128
#define BK 64
#define LDP 72    // padded LDS row (elements)
#define TLP 132   // padded epilogue row (elements)
__global__ __launch_bounds__(256) void k_vgemm(const float* __restrict__ x11,
                                               const unsigned short* __restrict__ W2t,
                                               const float* __restrict__ c1v,
                                               const float* __restrict__ c2v,
                                               unsigned short* __restrict__ V) {
    __shared__ unsigned short As[2][BM * LDP];   // 18.4 KB
    __shared__ unsigned short Bs[2][BN * LDP];   // 36.9 KB
    __shared__ float s_s1[BM], s_s2[BM], s_mu[BM], s_rs[BM];
    const int tid = threadIdx.x;
    const int lane = tid & 63;
    const int wv = tid >> 6;
    const int wr = wv >> 1, wc = wv & 1;
    const int lr = lane & 15, kh = lane >> 4;
    const int bm0 = (blockIdx.x >> 3) * BM;   // 64 m-tiles
    const int bn0 = (blockIdx.x & 7) * BN;    // 8 n-tiles

    // A staging: 64x64 fp32 tile = 1024 float4, 4/thread; convert->bf16 short4
    int aOff[4], aRow[4];
    const float4* gAx[4];
#pragma unroll
    for (int j = 0; j < 4; ++j) {
        int idx = j * 256 + tid;
        aRow[j] = idx >> 4;                 // 0..63
        int c4 = idx & 15;                  // float4 index within 64-col row
        aOff[j] = aRow[j] * LDP + c4 * 4;
        gAx[j] = (const float4*)(x11 + (size_t)(bm0 + aRow[j]) * ND) + c4;
    }
    // B staging: 128x64 bf16 tile = 1024 short8, 4/thread
    int bOff[4];
    const short8* gB[4];
#pragma unroll
    for (int j = 0; j < 4; ++j) {
        int idx = j * 256 + tid;
        int row = idx >> 3, c8 = idx & 7;
        bOff[j] = row * LDP + c8 * 8;
        gB[j] = (const short8*)(W2t + (size_t)(bn0 + row) * ND) + c8;
    }

    floatx4 acc[2][4];
#pragma unroll
    for (int m = 0; m < 2; ++m)
#pragma unroll
        for (int n = 0; n < 4; ++n) acc[m][n] = (floatx4){0.f, 0.f, 0.f, 0.f};

    float sa1[4], sa2[4];
#pragma unroll
    for (int j = 0; j < 4; ++j) { sa1[j] = 0.f; sa2[j] = 0.f; }

    float4 rax[4];
    short8 rb[4];
#pragma unroll
    for (int j = 0; j < 4; ++j) rax[j] = gAx[j][0];
#pragma unroll
    for (int j = 0; j < 4; ++j) rb[j] = gB[j][0];

    const int NT = ND / BK;   // 16
#pragma unroll 1
    for (int t = 0; t < NT; ++t) {
        unsigned short* Ab = As[t & 1];
        unsigned short* Bb = Bs[t & 1];
#pragma unroll
        for (int j = 0; j < 4; ++j) {
            float4 r = rax[j];
            sa1[j] += r.x + r.y + r.z + r.w;
            sa2[j] += r.x*r.x + r.y*r.y + r.z*r.z + r.w*r.w;
            short4v s; s[0] = f2bfs(r.x); s[1] = f2bfs(r.y); s[2] = f2bfs(r.z); s[3] = f2bfs(r.w);
            *(short4v*)&Ab[aOff[j]] = s;
        }
#pragma unroll
        for (int j = 0; j < 4; ++j) *(short8*)&Bb[bOff[j]] = rb[j];
        __syncthreads();                       // single barrier per tile
        if (t < NT - 1) {
#pragma unroll
            for (int j = 0; j < 4; ++j) rax[j] = gAx[j][(t + 1) * 16];
#pragma unroll
            for (int j = 0; j < 4; ++j) rb[j] = gB[j][(t + 1) * 8];
        }
#pragma unroll
        for (int kk = 0; kk < 2; ++kk) {
            short8 a[2], b[4];
#pragma unroll
            for (int m = 0; m < 2; ++m)
                a[m] = *(const short8*)&As[t & 1][(wr * 32 + m * 16 + lr) * LDP + kk * 32 + kh * 8];
#pragma unroll
            for (int n = 0; n < 4; ++n)
                b[n] = *(const short8*)&Bs[t & 1][(wc * 64 + n * 16 + lr) * LDP + kk * 32 + kh * 8];
#pragma unroll
            for (int m = 0; m < 2; ++m)
#pragma unroll
                for (int n = 0; n < 4; ++n)
                    acc[m][n] = __builtin_amdgcn_mfma_f32_16x16x32_bf16(a[m], b[n], acc[m][n], 0, 0, 0);
        }
    }

    // row stats: 16 threads share a row (consecutive lanes) -> shuffle-reduce
#pragma unroll
    for (int j = 0; j < 4; ++j) {
#pragma unroll
        for (int m = 1; m < 16; m <<= 1) {
            sa1[j] += __shfl_xor(sa1[j], m);
            sa2[j] += __shfl_xor(sa2[j], m);
        }
        if ((tid & 15) == 0) { s_s1[aRow[j]] = sa1[j]; s_s2[aRow[j]] = sa2[j]; }
    }
    __syncthreads();                            // stats visible + all loop ds_reads done
    if (tid < BM) {
        float mu = s_s1[tid] * (1.0f / ND);
        float var = s_s2[tid] * (1.0f / ND) - mu * mu;
        s_mu[tid] = mu;
        s_rs[tid] = rsqrtf(var + 1e-5f);
    }
    __syncthreads();

    // epilogue: v = rstd*y + c2v - rstd*mu*c1v ; stage to LDS, coalesced store
    unsigned short* Cs = (unsigned short*)As;   // 64*TLP*2B = 16.9 KB <= 18.4 KB
#pragma unroll
    for (int n = 0; n < 4; ++n) {
        const int coll = wc * 64 + n * 16 + lr;
        const float cc1 = c1v[bn0 + coll];
        const float cc2 = c2v[bn0 + coll];
#pragma unroll
        for (int m = 0; m < 2; ++m) {
#pragma unroll
            for (int r = 0; r < 4; ++r) {
                const int rowl = wr * 32 + m * 16 + kh * 4 + r;
                const float rs = s_rs[rowl];
                const float v = rs * acc[m][n][r] + cc2 - rs * s_mu[rowl] * cc1;
                Cs[rowl * TLP + coll] = f2bf(v);
            }
        }
    }
    __syncthreads();
#pragma unroll
    for (int j = 0; j < 4; ++j) {
        int idx = j * 256 + tid;                // 1024 short8s = 64 rows x 16
        int row = idx >> 4, c8 = idx & 15;
        *(short8*)&V[(size_t)(bm0 + row) * ND + bn0 + c8 * 8] = *(const short8*)&Cs[row * TLP + c8 * 8];
    }
}

// K3: stream all 12 layers per (b,s) row; LN-folded logits; softmax over depth;
// register-held weighted mix; gate; write out. V read as bf16.
__global__ void k_fused(const float* __restrict__ states, const unsigned short* __restrict__ V,
                        const float* __restrict__ lnw, const float* __restrict__ lnb,
                        const float* __restrict__ gatep, float* __restrict__ out) {
    __shared__ float s_logit[12];
    __shared__ float s_w12[12];
    __shared__ float s_g;
    __shared__ float s_part[4][ND];
    __shared__ float s_x11[ND];
    const int p = blockIdx.x;
    const int tid = threadIdx.x;
    const int lane = tid & 63;
    const int wv = tid >> 6;
    const size_t LS = (size_t)NBS * ND;
    const float* base = states + (size_t)p * ND;
    const short4v* Vp = (const short4v*)(V + (size_t)p * ND);

    float4 t[4];
    float red[11];
#pragma unroll
    for (int j = 0; j < 11; ++j) red[j] = 0.f;
#pragma unroll
    for (int i = 0; i < 4; ++i) {
        int idx = lane + 64 * i;
        short4v vq = Vp[idx];
        float4 v;
        v.x = bf2f(vq[0]); v.y = bf2f(vq[1]); v.z = bf2f(vq[2]); v.w = bf2f(vq[3]);
        float4 w = ((const float4*)lnw)[idx];
        float4 b = ((const float4*)lnb)[idx];
        float4 tt; tt.x = v.x*w.x; tt.y = v.y*w.y; tt.z = v.z*w.z; tt.w = v.w*w.w;
        t[i] = tt;
        red[9]  += tt.x + tt.y + tt.z + tt.w;
        red[10] += v.x*b.x + v.y*b.y + v.z*b.z + v.w*b.w;
    }

    float4 x[3][4];
#pragma unroll
    for (int rr = 0; rr < 3; ++rr) {
        const int l = wv + 4 * rr;
        const float4* xr = (const float4*)(base + (size_t)l * LS);
#pragma unroll
        for (int i = 0; i < 4; ++i) {
            float4 xx = xr[lane + 64 * i];
            x[rr][i] = xx;
            red[rr]     += xx.x + xx.y + xx.z + xx.w;
            red[3 + rr] += xx.x*xx.x + xx.y*xx.y + xx.z*xx.z + xx.w*xx.w;
            red[6 + rr] += xx.x*t[i].x + xx.y*t[i].y + xx.z*t[i].z + xx.w*t[i].w;
        }
    }
#pragma unroll
    for (int m = 32; m > 0; m >>= 1) {
#pragma unroll
        for (int j = 0; j < 11; ++j) red[j] += __shfl_xor(red[j], m);
    }
    if (lane == 0) {
#pragma unroll
        for (int rr = 0; rr < 3; ++rr) {
            float mu = red[rr] * (1.0f / ND);
            float var = red[3 + rr] * (1.0f / ND) - mu * mu;
            float rstd = rsqrtf(var + 1e-5f);
            s_logit[wv + 4 * rr] = 0.0625f * (rstd * (red[6 + rr] - mu * red[9]) + red[10]);
        }
    }
    __syncthreads();
    if (tid == 0) {
        float mx = s_logit[0];
#pragma unroll
        for (int l = 1; l < 12; ++l) mx = fmaxf(mx, s_logit[l]);
        float e[12], sum = 0.f;
#pragma unroll
        for (int l = 0; l < 12; ++l) { e[l] = expf(s_logit[l] - mx); sum += e[l]; }
        float inv = 1.0f / sum;
#pragma unroll
        for (int l = 0; l < 12; ++l) s_w12[l] = e[l] * inv;
        s_g = 1.0f / (1.0f + expf(-gatep[0]));
    }
    __syncthreads();

    const float w0 = s_w12[wv], w1 = s_w12[wv + 4], w2 = s_w12[wv + 8];
#pragma unroll
    for (int i = 0; i < 4; ++i) {
        int idx = lane + 64 * i;
        float4 pm;
        pm.x = w0*x[0][i].x + w1*x[1][i].x + w2*x[2][i].x;
        pm.y = w0*x[0][i].y + w1*x[1][i].y + w2*x[2][i].y;
        pm.z = w0*x[0][i].z + w1*x[1][i].z + w2*x[2][i].z;
        pm.w = w0*x[0][i].w + w1*x[1][i].w + w2*x[2][i].w;
        ((float4*)s_part[wv])[idx] = pm;
        if (wv == 3) ((float4*)s_x11)[idx] = x[2][i];   // wv=3, rr=2 -> l=11
    }
    __syncthreads();

    const float g = s_g;
    float4 a0 = ((const float4*)s_part[0])[tid];
    float4 a1 = ((const float4*)s_part[1])[tid];
    float4 a2 = ((const float4*)s_part[2])[tid];
    float4 a3 = ((const float4*)s_part[3])[tid];
    float4 x11 = ((const float4*)s_x11)[tid];
    float4 o;
    o.x = g * x11.x + (1.f - g) * (a0.x + a1.x + a2.x + a3.x);
    o.y = g * x11.y + (1.f - g) * (a0.y + a1.y + a2.y + a3.y);
    o.z = g * x11.z + (1.f - g) * (a0.z + a1.z + a2.z + a3.z);
    o.w = g * x11.w + (1.f - g) * (a0.w + a1.w + a2.w + a3.w);
    ((float4*)(out + (size_t)p * ND))[tid] = o;
}

extern "C" void kernel_launch(void* const* d_in, const int* in_sizes, int n_in,
                              void* d_out, int out_size, void* d_ws, size_t ws_size,
                              hipStream_t stream) {
    (void)in_sizes; (void)n_in; (void)out_size; (void)ws_size;
    const float* states = (const float*)d_in[0];
    const float* Wq     = (const float*)d_in[1];
    const float* Wk     = (const float*)d_in[2];
    const float* lnw    = (const float*)d_in[3];
    const float* lnb    = (const float*)d_in[4];
    const float* gate   = (const float*)d_in[5];
    float* out = (float*)d_out;
    char* ws = (char*)d_ws;

    unsigned short* W2t = (unsigned short*)(ws);                 // 2 MiB (ND x ND bf16)
    float*          c1v = (float*)        (ws + (2u << 20));     // 4 KiB
    float*          c2v = (float*)        (ws + (2u << 20) + 4096); // 4 KiB
    unsigned short* V   = (unsigned short*)(ws + (3u << 20));    // 8 MiB (NBS x ND bf16)
    const float* x11 = states + (size_t)(NL - 1) * NBS * ND;

    k_prep<<<dim3(264), dim3(256), 0, stream>>>(Wq, Wk, lnw, lnb, W2t, c1v, c2v);
    k_vgemm<<<dim3((NBS / BM) * (ND / BN)), dim3(256), 0, stream>>>(x11, W2t, c1v, c2v, V);
    k_fused<<<dim3(NBS), dim3(256), 0, stream>>>(states, V, lnw, lnb, gate, out);
}

// Round 7
// 72.971 us; speedup vs baseline: 1.5098x; 1.5098x over previous
//
#include <hip/hip_runtime.h>

#define NL 12
#define NB 2
#define NS 2048
#define ND 1024
#define NDK 256
#define NBS (NB*NS)   // 4096

typedef __attribute__((ext_vector_type(8))) short short8;
typedef __attribute__((ext_vector_type(4))) short short4v;
typedef __attribute__((ext_vector_type(4))) float floatx4;

__device__ __forceinline__ unsigned short f2bf(float f) {
    unsigned int u = __float_as_uint(f);
    u += 0x7FFFu + ((u >> 16) & 1u);
    return (unsigned short)(u >> 16);
}
__device__ __forceinline__ short f2bfs(float f) { return (short)f2bf(f); }
__device__ __forceinline__ float bf2f(short s) {
    return __uint_as_float(((unsigned int)(unsigned short)s) << 16);
}

// K1: blocks [0,256): W2t[d][d'] = sum_k Wk[k][d]*Wq[k][d']  (bf16 out, MFMA)
//     blocks [256, 256+4096): LayerNorm(states[11]) -> U bf16
// (LN blocks saturate the machine and hide the strided weight-GEMM latency —
//  round-6 lesson: do NOT strip them out.)
__global__ void k_prep_ln(const float* __restrict__ Wq, const float* __restrict__ Wk,
                          const float* __restrict__ x11,
                          const float* __restrict__ lnw, const float* __restrict__ lnb,
                          unsigned short* __restrict__ W2t, unsigned short* __restrict__ U) {
    const int tid = threadIdx.x;
    if (blockIdx.x < 256) {
        const int lane = tid & 63, wv = tid >> 6;
        const int wid = blockIdx.x * 4 + wv;      // 0..1023
        const int tm = wid >> 4;                  // d-tile (rows of W2t), 0..63
        const int tnb = wid & 15;                 // d'-tile (cols, 64 wide), 0..15
        const int lr = lane & 15, kh = lane >> 4;
        floatx4 acc[4];
#pragma unroll
        for (int c = 0; c < 4; ++c) acc[c] = (floatx4){0.f, 0.f, 0.f, 0.f};
#pragma unroll 2
        for (int kb = 0; kb < 8; ++kb) {
            const float* Ab = Wk + (size_t)(kb * 32 + kh * 8) * ND + tm * 16 + lr;
            const float* Bb = Wq + (size_t)(kb * 32 + kh * 8) * ND + tnb * 64 + lr;
            short8 a;
#pragma unroll
            for (int j = 0; j < 8; ++j) a[j] = f2bfs(Ab[(size_t)j * ND]);
#pragma unroll
            for (int c = 0; c < 4; ++c) {
                short8 b;
#pragma unroll
                for (int j = 0; j < 8; ++j) b[j] = f2bfs(Bb[(size_t)j * ND + c * 16]);
                acc[c] = __builtin_amdgcn_mfma_f32_16x16x32_bf16(a, b, acc[c], 0, 0, 0);
            }
        }
#pragma unroll
        for (int c = 0; c < 4; ++c)
#pragma unroll
            for (int r = 0; r < 4; ++r)
                W2t[(size_t)(tm * 16 + kh * 4 + r) * ND + tnb * 64 + c * 16 + lr] = f2bf(acc[c][r]);
        return;
    }
    __shared__ float red[8];
    const int p = blockIdx.x - 256;
    const float4* xr = (const float4*)(x11 + (size_t)p * ND);
    float4 x = xr[tid];
    float s1 = x.x + x.y + x.z + x.w;
    float s2 = x.x*x.x + x.y*x.y + x.z*x.z + x.w*x.w;
#pragma unroll
    for (int m = 32; m > 0; m >>= 1) { s1 += __shfl_xor(s1, m); s2 += __shfl_xor(s2, m); }
    int wv = tid >> 6;
    if ((tid & 63) == 0) { red[wv] = s1; red[4 + wv] = s2; }
    __syncthreads();
    float S1 = red[0] + red[1] + red[2] + red[3];
    float S2 = red[4] + red[5] + red[6] + red[7];
    float mu = S1 * (1.0f / ND);
    float var = S2 * (1.0f / ND) - mu * mu;
    float rstd = rsqrtf(var + 1e-5f);
    float4 w = ((const float4*)lnw)[tid];
    float4 b = ((const float4*)lnb)[tid];
    ushort4 u;
    u.x = f2bf((x.x - mu) * rstd * w.x + b.x);
    u.y = f2bf((x.y - mu) * rstd * w.y + b.y);
    u.z = f2bf((x.z - mu) * rstd * w.z + b.z);
    u.w = f2bf((x.w - mu) * rstd * w.w + b.w);
    ((ushort4*)U)[(size_t)p * (ND / 4) + tid] = u;
}

// K2: V (4096 x 1024 bf16) = U (4096 x 1024 bf16) @ W2t^T
// 64x128 tile, BK=64, double-buffered LDS, ONE barrier per K-tile.
// XCD-aware block swizzle: the 8 bn-blocks sharing one A row-block land on the
// SAME XCD (assumed bid%8 round-robin), so A re-reads hit the XCD-private L2.
#define BM 64
#define BN 128
#define BK 64
#define LDP 72    // padded LDS row (elements)
#define TLP 132   // padded epilogue row (elements)
__global__ __launch_bounds__(256) void k_vgemm(const unsigned short* __restrict__ U,
                                               const unsigned short* __restrict__ W2t,
                                               unsigned short* __restrict__ V) {
    __shared__ unsigned short As[2][BM * LDP];   // 18.4 KB
    __shared__ unsigned short Bs[2][BN * LDP];   // 36.9 KB
    const int tid = threadIdx.x;
    const int lane = tid & 63;
    const int wv = tid >> 6;
    const int wr = wv >> 1, wc = wv & 1;
    const int lr = lane & 15, kh = lane >> 4;
    // swizzle: xcd = bid&7, k = bid>>3 ; bm = xcd + 8*(k&7), bn = k>>3
    const int bid = blockIdx.x;                  // 512 blocks
    const int bm0 = ((bid & 7) + 8 * ((bid >> 3) & 7)) * BM;   // 64 m-tiles
    const int bn0 = (bid >> 6) * BN;                            // 8 n-tiles

    // staging maps: A 512 short8s (2/thread), B 1024 short8s (4/thread)
    int aOff[2], bOff[4];
    const short8* gA[2];
    const short8* gB[4];
#pragma unroll
    for (int j = 0; j < 2; ++j) {
        int idx = j * 256 + tid;
        int row = idx >> 3, c8 = idx & 7;
        aOff[j] = row * LDP + c8 * 8;
        gA[j] = (const short8*)(U + (size_t)(bm0 + row) * ND) + c8;
    }
#pragma unroll
    for (int j = 0; j < 4; ++j) {
        int idx = j * 256 + tid;
        int row = idx >> 3, c8 = idx & 7;
        bOff[j] = row * LDP + c8 * 8;
        gB[j] = (const short8*)(W2t + (size_t)(bn0 + row) * ND) + c8;
    }

    floatx4 acc[2][4];
#pragma unroll
    for (int m = 0; m < 2; ++m)
#pragma unroll
        for (int n = 0; n < 4; ++n) acc[m][n] = (floatx4){0.f, 0.f, 0.f, 0.f};

    short8 ra[2], rb[4];
#pragma unroll
    for (int j = 0; j < 2; ++j) ra[j] = gA[j][0];
#pragma unroll
    for (int j = 0; j < 4; ++j) rb[j] = gB[j][0];

    const int NT = ND / BK;   // 16
#pragma unroll 1
    for (int t = 0; t < NT; ++t) {
        unsigned short* Ab = As[t & 1];
        unsigned short* Bb = Bs[t & 1];
#pragma unroll
        for (int j = 0; j < 2; ++j) *(short8*)&Ab[aOff[j]] = ra[j];
#pragma unroll
        for (int j = 0; j < 4; ++j) *(short8*)&Bb[bOff[j]] = rb[j];
        __syncthreads();                       // single barrier per tile
        if (t < NT - 1) {                      // prefetch t+1 (lands during MFMA phase)
#pragma unroll
            for (int j = 0; j < 2; ++j) ra[j] = gA[j][(t + 1) * 8];
#pragma unroll
            for (int j = 0; j < 4; ++j) rb[j] = gB[j][(t + 1) * 8];
        }
#pragma unroll
        for (int kk = 0; kk < 2; ++kk) {
            short8 a[2], b[4];
#pragma unroll
            for (int m = 0; m < 2; ++m)
                a[m] = *(const short8*)&Ab[(wr * 32 + m * 16 + lr) * LDP + kk * 32 + kh * 8];
#pragma unroll
            for (int n = 0; n < 4; ++n)
                b[n] = *(const short8*)&Bb[(wc * 64 + n * 16 + lr) * LDP + kk * 32 + kh * 8];
#pragma unroll
            for (int m = 0; m < 2; ++m)
#pragma unroll
                for (int n = 0; n < 4; ++n)
                    acc[m][n] = __builtin_amdgcn_mfma_f32_16x16x32_bf16(a[m], b[n], acc[m][n], 0, 0, 0);
        }
    }

    // epilogue: stage C-tile (64x128 bf16) into LDS (reuse As), store coalesced
    __syncthreads();                            // all ds_reads of the loop done
    unsigned short* Cs = (unsigned short*)As;   // 64*TLP = 16.9 KB <= 18.4 KB
#pragma unroll
    for (int m = 0; m < 2; ++m)
#pragma unroll
        for (int n = 0; n < 4; ++n)
#pragma unroll
            for (int r = 0; r < 4; ++r)
                Cs[(wr * 32 + m * 16 + kh * 4 + r) * TLP + wc * 64 + n * 16 + lr] = f2bf(acc[m][n][r]);
    __syncthreads();
#pragma unroll
    for (int j = 0; j < 4; ++j) {
        int idx = j * 256 + tid;                // 1024 short8s = 64 rows x 16
        int row = idx >> 4, c8 = idx & 15;
        *(short8*)&V[(size_t)(bm0 + row) * ND + bn0 + c8 * 8] = *(const short8*)&Cs[row * TLP + c8 * 8];
    }
}

// K3: stream all 12 layers per (b,s) row; LN-folded logits; softmax over depth;
// register-held weighted mix; gate; write out. V read as bf16.
__global__ void k_fused(const float* __restrict__ states, const unsigned short* __restrict__ V,
                        const float* __restrict__ lnw, const float* __restrict__ lnb,
                        const float* __restrict__ gatep, float* __restrict__ out) {
    __shared__ float s_logit[12];
    __shared__ float s_w12[12];
    __shared__ float s_g;
    __shared__ float s_part[4][ND];
    __shared__ float s_x11[ND];
    const int p = blockIdx.x;
    const int tid = threadIdx.x;
    const int lane = tid & 63;
    const int wv = tid >> 6;
    const size_t LS = (size_t)NBS * ND;
    const float* base = states + (size_t)p * ND;
    const short4v* Vp = (const short4v*)(V + (size_t)p * ND);

    float4 t[4];
    float red[11];
#pragma unroll
    for (int j = 0; j < 11; ++j) red[j] = 0.f;
#pragma unroll
    for (int i = 0; i < 4; ++i) {
        int idx = lane + 64 * i;
        short4v vq = Vp[idx];
        float4 v;
        v.x = bf2f(vq[0]); v.y = bf2f(vq[1]); v.z = bf2f(vq[2]); v.w = bf2f(vq[3]);
        float4 w = ((const float4*)lnw)[idx];
        float4 b = ((const float4*)lnb)[idx];
        float4 tt; tt.x = v.x*w.x; tt.y = v.y*w.y; tt.z = v.z*w.z; tt.w = v.w*w.w;
        t[i] = tt;
        red[9]  += tt.x + tt.y + tt.z + tt.w;
        red[10] += v.x*b.x + v.y*b.y + v.z*b.z + v.w*b.w;
    }

    float4 x[3][4];
#pragma unroll
    for (int rr = 0; rr < 3; ++rr) {
        const int l = wv + 4 * rr;
        const float4* xr = (const float4*)(base + (size_t)l * LS);
#pragma unroll
        for (int i = 0; i < 4; ++i) {
            float4 xx = xr[lane + 64 * i];
            x[rr][i] = xx;
            red[rr]     += xx.x + xx.y + xx.z + xx.w;
            red[3 + rr] += xx.x*xx.x + xx.y*xx.y + xx.z*xx.z + xx.w*xx.w;
            red[6 + rr] += xx.x*t[i].x + xx.y*t[i].y + xx.z*t[i].z + xx.w*t[i].w;
        }
    }
#pragma unroll
    for (int m = 32; m > 0; m >>= 1) {
#pragma unroll
        for (int j = 0; j < 11; ++j) red[j] += __shfl_xor(red[j], m);
    }
    if (lane == 0) {
#pragma unroll
        for (int rr = 0; rr < 3; ++rr) {
            float mu = red[rr] * (1.0f / ND);
            float var = red[3 + rr] * (1.0f / ND) - mu * mu;
            float rstd = rsqrtf(var + 1e-5f);
            s_logit[wv + 4 * rr] = 0.0625f * (rstd * (red[6 + rr] - mu * red[9]) + red[10]);
        }
    }
    __syncthreads();
    if (tid == 0) {
        float mx = s_logit[0];
#pragma unroll
        for (int l = 1; l < 12; ++l) mx = fmaxf(mx, s_logit[l]);
        float e[12], sum = 0.f;
#pragma unroll
        for (int l = 0; l < 12; ++l) { e[l] = expf(s_logit[l] - mx); sum += e[l]; }
        float inv = 1.0f / sum;
#pragma unroll
        for (int l = 0; l < 12; ++l) s_w12[l] = e[l] * inv;
        s_g = 1.0f / (1.0f + expf(-gatep[0]));
    }
    __syncthreads();

    const float w0 = s_w12[wv], w1 = s_w12[wv + 4], w2 = s_w12[wv + 8];
#pragma unroll
    for (int i = 0; i < 4; ++i) {
        int idx = lane + 64 * i;
        float4 pm;
        pm.x = w0*x[0][i].x + w1*x[1][i].x + w2*x[2][i].x;
        pm.y = w0*x[0][i].y + w1*x[1][i].y + w2*x[2][i].y;
        pm.z = w0*x[0][i].z + w1*x[1][i].z + w2*x[2][i].z;
        pm.w = w0*x[0][i].w + w1*x[1][i].w + w2*x[2][i].w;
        ((float4*)s_part[wv])[idx] = pm;
        if (wv == 3) ((float4*)s_x11)[idx] = x[2][i];   // wv=3, rr=2 -> l=11
    }
    __syncthreads();

    const float g = s_g;
    float4 a0 = ((const float4*)s_part[0])[tid];
    float4 a1 = ((const float4*)s_part[1])[tid];
    float4 a2 = ((const float4*)s_part[2])[tid];
    float4 a3 = ((const float4*)s_part[3])[tid];
    float4 x11 = ((const float4*)s_x11)[tid];
    float4 o;
    o.x = g * x11.x + (1.f - g) * (a0.x + a1.x + a2.x + a3.x);
    o.y = g * x11.y + (1.f - g) * (a0.y + a1.y + a2.y + a3.y);
    o.z = g * x11.z + (1.f - g) * (a0.z + a1.z + a2.z + a3.z);
    o.w = g * x11.w + (1.f - g) * (a0.w + a1.w + a2.w + a3.w);
    ((float4*)(out + (size_t)p * ND))[tid] = o;
}

extern "C" void kernel_launch(void* const* d_in, const int* in_sizes, int n_in,
                              void* d_out, int out_size, void* d_ws, size_t ws_size,
                              hipStream_t stream) {
    (void)in_sizes; (void)n_in; (void)out_size; (void)ws_size;
    const float* states = (const float*)d_in[0];
    const float* Wq     = (const float*)d_in[1];
    const float* Wk     = (const float*)d_in[2];
    const float* lnw    = (const float*)d_in[3];
    const float* lnb    = (const float*)d_in[4];
    const float* gate   = (const float*)d_in[5];
    float* out = (float*)d_out;
    char* ws = (char*)d_ws;

    unsigned short* U   = (unsigned short*)(ws);                // 8 MiB  (NBS x ND bf16)
    unsigned short* W2t = (unsigned short*)(ws + (9u << 20));   // 2 MiB  (ND x ND bf16)
    unsigned short* V   = (unsigned short*)(ws + (12u << 20));  // 8 MiB  (NBS x ND bf16)

    k_prep_ln<<<dim3(256 + NBS), dim3(256), 0, stream>>>(
        Wq, Wk, states + (size_t)(NL - 1) * NBS * ND, lnw, lnb, W2t, U);
    k_vgemm<<<dim3((NBS / BM) * (ND / BN)), dim3(256), 0, stream>>>(U, W2t, V);
    k_fused<<<dim3(NBS), dim3(256), 0, stream>>>(states, V, lnw, lnb, gate, out);
}